// Round 6
// baseline (166.811 us; speedup 1.0000x reference)
//
#include <hip/hip_runtime.h>
#include <hip/hip_bf16.h>
#include <stdint.h>

#define NB 8
#define NS 1024
#define DM 768
#define NH 12
#define DH 64
#define NE 2304            // 3*DM
#define MTOT (NB*NS)       // 8192

typedef unsigned short u16;
typedef __attribute__((ext_vector_type(8))) __bf16 bf16x8;
typedef __attribute__((ext_vector_type(4))) float floatx4;
typedef __attribute__((ext_vector_type(4))) uint32_t uint32x4;

// ---- workspace layout (bytes) ----
#define WS_XB  0ull                    // x bf16 [8192][768]
#define WS_WT  12582912ull             // wt bf16 [3][768 n=h*64+d][768 k]
#define WS_BR  16121856ull             // bias f32 [3][768] (Q prescaled)
#define WS_QB  16131072ull             // Q bf16 [96][1024][64] (pre-scaled)
#define WS_KB  28713984ull             // K bf16 [96][1024][64]
#define WS_VT  41296896ull             // V^T bf16 [96][64][1024]

#define QSC 0.05206490030275093f       // 768^-0.5 * log2(e)

__device__ __forceinline__ u16 f2bf(float f) {
  union { float f; uint32_t u; } v; v.f = f;
  uint32_t r = (v.u + 0x7fffu + ((v.u >> 16) & 1u)) >> 16;   // RNE
  return (u16)r;
}

__device__ __forceinline__ void gload16(const void* g, void* l) {
  __builtin_amdgcn_global_load_lds(
      (const __attribute__((address_space(1))) void*)g,
      (__attribute__((address_space(3))) void*)l, 16, 0, 0);
}

// ---------------- convert x -> bf16 ----------------
__global__ void conv_x_kernel(const float4* __restrict__ x, u16* __restrict__ xb, int n4) {
  int i = blockIdx.x * blockDim.x + threadIdx.x;
  int stride = gridDim.x * blockDim.x;
  for (; i < n4; i += stride) {
    float4 v = x[i];
    ushort4 r;
    r.x = f2bf(v.x); r.y = f2bf(v.y); r.z = f2bf(v.z); r.w = f2bf(v.w);
    ((ushort4*)xb)[i] = r;
  }
}

// ---------------- bias de-interleave: br[c][h*64+d] = b[h*192+d*3+c] ----------------
__global__ void prep_bias_kernel(const float* __restrict__ b, float* __restrict__ br) {
  const int o = blockIdx.x * 256 + threadIdx.x;
  if (o < 3 * DM) {
    const int c = o / DM, n = o % DM;
    const int h = n >> 6, d = n & 63;
    float v = b[h * 192 + d * 3 + c];
    if (c == 0) v *= QSC;
    br[o] = v;
  }
}

// ---------------- weights: w[768k][2304e] f32 -> wt[c][n=h*64+d][k] bf16 ----------------
__global__ void transpose_w_kernel(const float* __restrict__ w, u16* __restrict__ wt) {
  __shared__ float tile[32][33];
  const int e0 = blockIdx.x * 32, k0 = blockIdx.y * 32;
  const int tx = threadIdx.x, ty = threadIdx.y;   // block (32,8)
#pragma unroll
  for (int i = 0; i < 4; i++)
    tile[ty + i*8][tx] = w[(size_t)(k0 + ty + i*8) * NE + e0 + tx];
  __syncthreads();
#pragma unroll
  for (int i = 0; i < 4; i++) {
    const int e = e0 + ty + i*8;
    const int c = e % 3, h = e / 192, d = (e % 192) / 3;
    const float sc = (c == 0) ? QSC : 1.0f;
    wt[((size_t)c * DM + h*64 + d) * DM + k0 + tx] = f2bf(tile[tx][ty + i*8] * sc);
  }
}

// ---------------- unified QKV GEMM: 3-deep counted-vmcnt pipeline (T4) ----------------
// grid (64 m, 6 n, 3 cls); BM=BN=128, BK=32, 4 waves, triple-buffered LDS.
// Loads for tiles t+1,t+2 stay in flight across barriers; vmcnt(8) only
// retires tile t. Q/K: acc=mfma(af,bfr)->C[m][n]; V: acc=mfma(bfr,af)->C^T.
__global__ __launch_bounds__(256) void qkv_gemm_kernel(
    const u16* __restrict__ xb, const u16* __restrict__ wt,
    const float* __restrict__ br,
    u16* __restrict__ qb, u16* __restrict__ kb, u16* __restrict__ vtb) {
  __shared__ __align__(16) u16 a_lds[3][128 * 32];
  __shared__ __align__(16) u16 b_lds[3][128 * 32];
  const int t  = threadIdx.x;
  const int w  = t >> 6, l = t & 63;
  const int wr = w >> 1, wc = w & 1;
  const int lq = l & 15, lg = l >> 4;
  const int m0  = (int)blockIdx.x * 128;
  const int n0  = (int)blockIdx.y * 128;
  const int cls = (int)blockIdx.z;

  floatx4 z = {0.f, 0.f, 0.f, 0.f};
  floatx4 acc[4][4];
#pragma unroll
  for (int i = 0; i < 4; i++)
#pragma unroll
    for (int j = 0; j < 4; j++) acc[i][j] = z;

  const int srow = t >> 2;
  const int scb  = (t & 3) ^ ((t >> 3) & 3);
  const u16* ga = xb + (size_t)m0 * DM + scb * 8;
  const u16* gb = wt + ((size_t)cls * DM + n0) * DM + scb * 8;
  const int rswz = (lq >> 1) & 3;

#define STAGE(buf, k0)                                                            \
  {                                                                               \
    _Pragma("unroll")                                                             \
    for (int i = 0; i < 2; i++) {                                                 \
      gload16(ga + (size_t)(i*64 + srow) * DM + (k0), (char*)a_lds[buf] + i*4096 + w*1024); \
      gload16(gb + (size_t)(i*64 + srow) * DM + (k0), (char*)b_lds[buf] + i*4096 + w*1024); \
    }                                                                             \
  }

#define COMPUTE(buf)                                                              \
  {                                                                               \
    bf16x8 af[4], bfr[4];                                                         \
    _Pragma("unroll")                                                             \
    for (int i = 0; i < 4; i++)                                                   \
      af[i] = *(const bf16x8*)((const char*)a_lds[buf] + (wr*64 + i*16 + lq)*64 + ((lg ^ rswz) * 16)); \
    _Pragma("unroll")                                                             \
    for (int j = 0; j < 4; j++)                                                   \
      bfr[j] = *(const bf16x8*)((const char*)b_lds[buf] + (wc*64 + j*16 + lq)*64 + ((lg ^ rswz) * 16)); \
    if (cls == 2) {                                                               \
      _Pragma("unroll")                                                           \
      for (int i = 0; i < 4; i++)                                                 \
        _Pragma("unroll")                                                         \
        for (int j = 0; j < 4; j++)                                               \
          acc[i][j] = __builtin_amdgcn_mfma_f32_16x16x32_bf16(bfr[j], af[i], acc[i][j], 0, 0, 0); \
    } else {                                                                      \
      _Pragma("unroll")                                                           \
      for (int i = 0; i < 4; i++)                                                 \
        _Pragma("unroll")                                                         \
        for (int j = 0; j < 4; j++)                                               \
          acc[i][j] = __builtin_amdgcn_mfma_f32_16x16x32_bf16(af[i], bfr[j], acc[i][j], 0, 0, 0); \
    }                                                                             \
  }

  // prologue: tiles 0 and 1 in flight (8 loads/wave)
  STAGE(0, 0);
  STAGE(1, 32);
  // main loop: tiles 0..21. Stage t+2; wait for tile t only (8 newest stay in flight).
  for (int kt = 0; kt < 22; ++kt) {
    STAGE((kt + 2) % 3, 32 * (kt + 2));
    asm volatile("s_waitcnt vmcnt(8)" ::: "memory");
    __builtin_amdgcn_s_barrier();
    COMPUTE(kt % 3);
    asm volatile("" ::: "memory");
    __builtin_amdgcn_s_barrier();
  }
  // tile 22: only tile 23's 4 loads may remain in flight
  asm volatile("s_waitcnt vmcnt(4)" ::: "memory");
  __builtin_amdgcn_s_barrier();
  COMPUTE(1);
  asm volatile("" ::: "memory");
  __builtin_amdgcn_s_barrier();
  // tile 23
  asm volatile("s_waitcnt vmcnt(0)" ::: "memory");
  __builtin_amdgcn_s_barrier();
  COMPUTE(2);
#undef STAGE
#undef COMPUTE

  if (cls != 2) {
    // C[m][n]: lane (lq,lg) holds m = m0+wr*64+i*16+lg*4+r, n = n0+wc*64+j*16+lq
    u16* dst = (cls == 0) ? qb : kb;
#pragma unroll
    for (int j = 0; j < 4; j++) {
      const int n  = n0 + wc*64 + j*16 + lq;
      const int h  = n >> 6, d = n & 63;
      const float bv = br[cls * DM + n];
#pragma unroll
      for (int i = 0; i < 4; i++) {
        const int mb = m0 + wr*64 + i*16 + lg*4;
#pragma unroll
        for (int r = 0; r < 4; r++) {
          const int m = mb + r;
          const int bb = m >> 10, nn = m & 1023;
          dst[(((size_t)(bb * NH + h)) * NS + nn) * DH + d] = f2bf(acc[i][j][r] + bv);
        }
      }
    }
  } else {
    // C^T[n][m]: lane (lq,lg) holds n = n0+wc*64+j*16+lg*4+r, m = m0+wr*64+i*16+lq
    const int hq = (n0 + wc*64) >> 6;            // head fixed per wave quadrant
#pragma unroll
    for (int j = 0; j < 4; j++) {
      float bvv[4];
#pragma unroll
      for (int r = 0; r < 4; r++)
        bvv[r] = br[2 * DM + n0 + wc*64 + j*16 + lg*4 + r];
#pragma unroll
      for (int i = 0; i < 4; i++) {
        const int m = m0 + wr*64 + i*16 + lq;
        const int bb = m >> 10, nn = m & 1023;
#pragma unroll
        for (int r = 0; r < 4; r++) {
          const int d = (j*16 + lg*4 + r) & 63;
          vtb[(((size_t)(bb * NH + hq)) * DH + d) * NS + nn] = f2bf(acc[i][j][r] + bvv[r]);
        }
      }
    }
  }
}

// ---------------- flash attention (unchanged from round 3) ----------------
__global__ __launch_bounds__(256) void attn_kernel(
    const u16* __restrict__ qb, const u16* __restrict__ kb,
    const u16* __restrict__ vtb, float* __restrict__ out) {
  __shared__ __align__(16) u16 k_lds[64 * 64];
  __shared__ __align__(16) u16 v_lds[64 * 64];

  const int t = threadIdx.x, w = t >> 6, l = t & 63;
  const int bh = blockIdx.x >> 3, qblk = blockIdx.x & 7;
  const int bb = bh / NH, h = bh % NH;
  const int q0 = qblk * 128 + w * 32;
  const int lq = l & 15, lg = l >> 4;

  bf16x8 qf[2][2];
#pragma unroll
  for (int qt = 0; qt < 2; qt++) {
    const u16* qrow = qb + ((size_t)bh * NS + q0 + qt*16 + lq) * DH;
#pragma unroll
    for (int ds = 0; ds < 2; ds++)
      qf[qt][ds] = *(const bf16x8*)&qrow[lg*8 + ds*32];
  }

  float m2[2]    = {4.0f, 4.0f};
  float lsumP[2] = {0.f, 0.f};
  floatx4 z = {0.f, 0.f, 0.f, 0.f};
  floatx4 o[2][4];
#pragma unroll
  for (int qt = 0; qt < 2; qt++)
#pragma unroll
    for (int dt = 0; dt < 4; dt++) o[qt][dt] = z;

  const int srow = t >> 3;
  const int scb  = (t & 7) ^ (srow & 7);

  for (int kt0 = 0; kt0 < 16; kt0++) {
    const int k0 = kt0 * 64;
    __syncthreads();
#pragma unroll
    for (int i = 0; i < 2; i++) {
      const int row = i*32 + srow;
      gload16(kb  + ((size_t)bh * NS + k0 + row) * DH + scb*8, (char*)k_lds + i*4096 + w*1024);
      gload16(vtb + ((size_t)bh * DH + row) * NS + k0 + scb*8, (char*)v_lds + i*4096 + w*1024);
    }
    __syncthreads();

#pragma unroll
    for (int half = 0; half < 2; half++) {
      bf16x8 kf[2][2];
#pragma unroll
      for (int kt = 0; kt < 2; kt++) {
        const int krow = half*32 + ((lq >> 2) << 3) + kt*4 + (lq & 3);
#pragma unroll
        for (int ds = 0; ds < 2; ds++)
          kf[kt][ds] = *(const bf16x8*)((const char*)k_lds + krow*128 + ((ds*4 + lg) ^ (krow & 7))*16);
      }
      bf16x8 vf[4];
#pragma unroll
      for (int dt = 0; dt < 4; dt++) {
        const int vrow = dt*16 + lq;
        vf[dt] = *(const bf16x8*)((const char*)v_lds + vrow*128 + ((half*4 + lg) ^ (vrow & 7))*16);
      }

#pragma unroll
      for (int qt = 0; qt < 2; qt++) {
        floatx4 st0 = z, st1 = z;
        st0 = __builtin_amdgcn_mfma_f32_16x16x32_bf16(kf[0][0], qf[qt][0], st0, 0, 0, 0);
        st0 = __builtin_amdgcn_mfma_f32_16x16x32_bf16(kf[0][1], qf[qt][1], st0, 0, 0, 0);
        st1 = __builtin_amdgcn_mfma_f32_16x16x32_bf16(kf[1][0], qf[qt][0], st1, 0, 0, 0);
        st1 = __builtin_amdgcn_mfma_f32_16x16x32_bf16(kf[1][1], qf[qt][1], st1, 0, 0, 0);

        float p[8];
#pragma unroll
        for (int r = 0; r < 4; r++) { p[r] = st0[r]; p[4 + r] = st1[r]; }
        const float pmax = fmaxf(fmaxf(fmaxf(p[0], p[1]), fmaxf(p[2], p[3])),
                                 fmaxf(fmaxf(p[4], p[5]), fmaxf(p[6], p[7])));

        if (!__all(pmax - m2[qt] <= 8.0f)) {
          float mt = pmax;
          mt = fmaxf(mt, __shfl_xor(mt, 16));
          mt = fmaxf(mt, __shfl_xor(mt, 32));
          const float mnew = fmaxf(m2[qt], mt);
          const float corr = exp2f(m2[qt] - mnew);
          lsumP[qt] *= corr;
          float cr[4];
#pragma unroll
          for (int r = 0; r < 4; r++) cr[r] = __shfl(corr, lg*4 + r);
#pragma unroll
          for (int dt = 0; dt < 4; dt++)
#pragma unroll
            for (int r = 0; r < 4; r++) o[qt][dt][r] *= cr[r];
          m2[qt] = mnew;
        }

        const float m = m2[qt];
        float ls = 0.f;
        u16 pb[8];
#pragma unroll
        for (int e = 0; e < 8; e++) {
          const float pe = exp2f(p[e] - m);
          ls += pe;
          pb[e] = f2bf(pe);
        }
        lsumP[qt] += ls;

        uint32x4 pw;
        pw.x = (uint32_t)pb[0] | ((uint32_t)pb[1] << 16);
        pw.y = (uint32_t)pb[2] | ((uint32_t)pb[3] << 16);
        pw.z = (uint32_t)pb[4] | ((uint32_t)pb[5] << 16);
        pw.w = (uint32_t)pb[6] | ((uint32_t)pb[7] << 16);
        const bf16x8 pa = __builtin_bit_cast(bf16x8, pw);

#pragma unroll
        for (int dt = 0; dt < 4; dt++)
          o[qt][dt] = __builtin_amdgcn_mfma_f32_16x16x32_bf16(pa, vf[dt], o[qt][dt], 0, 0, 0);
      }
    }
  }

#pragma unroll
  for (int qt = 0; qt < 2; qt++) {
    float ls = lsumP[qt];
    ls += __shfl_xor(ls, 16);
    ls += __shfl_xor(ls, 32);
    const float inv = 1.0f / ls;
    float ir[4];
#pragma unroll
    for (int r = 0; r < 4; r++) ir[r] = __shfl(inv, lg*4 + r);
#pragma unroll
    for (int dt = 0; dt < 4; dt++)
#pragma unroll
      for (int r = 0; r < 4; r++) {
        const int n = q0 + qt*16 + lg*4 + r;
        out[((size_t)bb * NS + n) * DM + h*DH + dt*16 + lq] = o[qt][dt][r] * ir[r];
      }
  }
}

extern "C" void kernel_launch(void* const* d_in, const int* in_sizes, int n_in,
                              void* d_out, int out_size, void* d_ws, size_t ws_size,
                              hipStream_t stream) {
  const float* x     = (const float*)d_in[0];
  const float* w_qkv = (const float*)d_in[1];
  const float* b_qkv = (const float*)d_in[2];
  float* out = (float*)d_out;
  char* ws = (char*)d_ws;

  u16* xb   = (u16*)(ws + WS_XB);
  u16* wt   = (u16*)(ws + WS_WT);
  float* br = (float*)(ws + WS_BR);
  u16* qb   = (u16*)(ws + WS_QB);
  u16* kb   = (u16*)(ws + WS_KB);
  u16* vtb  = (u16*)(ws + WS_VT);

  conv_x_kernel<<<1024, 256, 0, stream>>>((const float4*)x, xb, MTOT * DM / 4);
  prep_bias_kernel<<<9, 256, 0, stream>>>(b_qkv, br);
  transpose_w_kernel<<<dim3(NE/32, DM/32), dim3(32, 8), 0, stream>>>(w_qkv, wt);
  qkv_gemm_kernel<<<dim3(MTOT/128, DM/128, 3), 256, 0, stream>>>(xb, wt, br, qb, kb, vtb);
  attn_kernel<<<(NB*NH) * (NS/128), 256, 0, stream>>>(qb, kb, vtb, out);
}

// Round 7
// 133.319 us; speedup vs baseline: 1.2512x; 1.2512x over previous
//
#include <hip/hip_runtime.h>
#include <hip/hip_bf16.h>
#include <stdint.h>

#define NB 8
#define NS 1024
#define DM 768
#define NH 12
#define DH 64
#define NE 2304            // 3*DM
#define MTOT (NB*NS)       // 8192

typedef unsigned short u16;
typedef __attribute__((ext_vector_type(8))) __bf16 bf16x8;
typedef __attribute__((ext_vector_type(4))) float floatx4;
typedef __attribute__((ext_vector_type(4))) uint32_t uint32x4;

// ---- workspace layout (bytes) ----
#define WS_XB  0ull                    // x bf16 [8192][768]
#define WS_WT  12582912ull             // wt bf16 [3][768 n=h*64+d][768 k]
#define WS_BR  16121856ull             // bias f32 [3][768] (Q prescaled)
#define WS_QB  16131072ull             // Q bf16 [96][1024][64] (pre-scaled)
#define WS_KB  28713984ull             // K bf16 [96][1024][64]
#define WS_VT  41296896ull             // V^T bf16 [96][64][1024]

#define QSC 0.05206490030275093f       // 768^-0.5 * log2(e)

__device__ __forceinline__ u16 f2bf(float f) {
  union { float f; uint32_t u; } v; v.f = f;
  uint32_t r = (v.u + 0x7fffu + ((v.u >> 16) & 1u)) >> 16;   // RNE
  return (u16)r;
}

__device__ __forceinline__ void gload16(const void* g, void* l) {
  __builtin_amdgcn_global_load_lds(
      (const __attribute__((address_space(1))) void*)g,
      (__attribute__((address_space(3))) void*)l, 16, 0, 0);
}

// ---------------- convert x -> bf16 ----------------
__global__ void conv_x_kernel(const float4* __restrict__ x, u16* __restrict__ xb, int n4) {
  int i = blockIdx.x * blockDim.x + threadIdx.x;
  int stride = gridDim.x * blockDim.x;
  for (; i < n4; i += stride) {
    float4 v = x[i];
    ushort4 r;
    r.x = f2bf(v.x); r.y = f2bf(v.y); r.z = f2bf(v.z); r.w = f2bf(v.w);
    ((ushort4*)xb)[i] = r;
  }
}

// ---------------- bias de-interleave: br[c][h*64+d] = b[h*192+d*3+c] ----------------
__global__ void prep_bias_kernel(const float* __restrict__ b, float* __restrict__ br) {
  const int o = blockIdx.x * 256 + threadIdx.x;
  if (o < 3 * DM) {
    const int c = o / DM, n = o % DM;
    const int h = n >> 6, d = n & 63;
    float v = b[h * 192 + d * 3 + c];
    if (c == 0) v *= QSC;
    br[o] = v;
  }
}

// ---------------- weights: w[768k][2304e] f32 -> wt[c][n=h*64+d][k] bf16 ----------------
__global__ void transpose_w_kernel(const float* __restrict__ w, u16* __restrict__ wt) {
  __shared__ float tile[32][33];
  const int e0 = blockIdx.x * 32, k0 = blockIdx.y * 32;
  const int tx = threadIdx.x, ty = threadIdx.y;   // block (32,8)
#pragma unroll
  for (int i = 0; i < 4; i++)
    tile[ty + i*8][tx] = w[(size_t)(k0 + ty + i*8) * NE + e0 + tx];
  __syncthreads();
#pragma unroll
  for (int i = 0; i < 4; i++) {
    const int e = e0 + ty + i*8;
    const int c = e % 3, h = e / 192, d = (e % 192) / 3;
    const float sc = (c == 0) ? QSC : 1.0f;
    wt[((size_t)c * DM + h*64 + d) * DM + k0 + tx] = f2bf(tile[tx][ty + i*8] * sc);
  }
}

// ---------------- unified QKV GEMM: 1-wave blocks, barrier-free pipeline ----------------
// 64x64 tile per 64-thread block; 4608 blocks. Each wave runs a private
// double-buffered counted-vmcnt pipeline (no __syncthreads anywhere).
// XCD band swizzle: bid&7 -> XCD owns a 1024-row A-band (L2-resident),
// m-fastest within band so consecutive blocks share the wt n-panel.
// Q/K: acc=mfma(af,bfr)->C[m][n];  V: acc=mfma(bfr,af)->C^T[n][m].
__global__ __launch_bounds__(64, 4) void qkv_gemm_kernel(
    const u16* __restrict__ xb, const u16* __restrict__ wt,
    const float* __restrict__ br,
    u16* __restrict__ qb, u16* __restrict__ kb, u16* __restrict__ vtb) {
  __shared__ __align__(16) u16 a_lds[2][64 * 32];
  __shared__ __align__(16) u16 b_lds[2][64 * 32];
  const int t  = threadIdx.x;            // 0..63
  const int lq = t & 15, lg = t >> 4;

  const int bid    = (int)blockIdx.x;
  const int xcd    = bid & 7;
  const int within = bid >> 3;           // 0..575
  const int mi     = within & 15;        // m fastest: share wt panel in L2
  const int ni     = within >> 4;        // 0..35
  const int m0     = (xcd * 16 + mi) * 64;
  const int cls    = ni / 12;
  const int nb     = ni % 12;
  const int n0     = nb * 64;

  floatx4 z = {0.f, 0.f, 0.f, 0.f};
  floatx4 acc[4][4];
#pragma unroll
  for (int i = 0; i < 4; i++)
#pragma unroll
    for (int j = 0; j < 4; j++) acc[i][j] = z;

  // staging: gload i covers rows i*16 + t/4; 16B-block (t&3) ^ ((row>>1)&3)
  const int srow = t >> 2;               // 0..15
  const int scb  = (t & 3) ^ ((t >> 3) & 3);
  const u16* ga = xb + (size_t)m0 * DM + scb * 8;
  const u16* gb = wt + ((size_t)cls * DM + n0) * DM + scb * 8;
  const int rswz = (lq >> 1) & 3;

#define STAGE(buf, k0)                                                            \
  {                                                                               \
    _Pragma("unroll")                                                             \
    for (int i = 0; i < 4; i++) {                                                 \
      gload16(ga + (size_t)(i*16 + srow) * DM + (k0), (char*)a_lds[buf] + i*1024); \
      gload16(gb + (size_t)(i*16 + srow) * DM + (k0), (char*)b_lds[buf] + i*1024); \
    }                                                                             \
  }

#define COMPUTE(buf)                                                              \
  {                                                                               \
    bf16x8 af[4], bfr[4];                                                         \
    _Pragma("unroll")                                                             \
    for (int i = 0; i < 4; i++)                                                   \
      af[i] = *(const bf16x8*)((const char*)a_lds[buf] + (i*16 + lq)*64 + ((lg ^ rswz) * 16)); \
    _Pragma("unroll")                                                             \
    for (int j = 0; j < 4; j++)                                                   \
      bfr[j] = *(const bf16x8*)((const char*)b_lds[buf] + (j*16 + lq)*64 + ((lg ^ rswz) * 16)); \
    if (cls == 2) {                                                               \
      _Pragma("unroll")                                                           \
      for (int i = 0; i < 4; i++)                                                 \
        _Pragma("unroll")                                                         \
        for (int j = 0; j < 4; j++)                                               \
          acc[i][j] = __builtin_amdgcn_mfma_f32_16x16x32_bf16(bfr[j], af[i], acc[i][j], 0, 0, 0); \
    } else {                                                                      \
      _Pragma("unroll")                                                           \
      for (int i = 0; i < 4; i++)                                                 \
        _Pragma("unroll")                                                         \
        for (int j = 0; j < 4; j++)                                               \
          acc[i][j] = __builtin_amdgcn_mfma_f32_16x16x32_bf16(af[i], bfr[j], acc[i][j], 0, 0, 0); \
    }                                                                             \
  }

  // barrier-free per-wave pipeline over 24 K-tiles (BK=32)
  STAGE(0, 0);
  int cur = 0;
  for (int kt = 0; kt < 23; ++kt) {
    // close write-after-read on the buffer we're about to refill
    asm volatile("s_waitcnt lgkmcnt(0)" ::: "memory");
    STAGE(cur ^ 1, 32 * (kt + 1));
    asm volatile("s_waitcnt vmcnt(8)" ::: "memory");   // tile kt landed; kt+1 in flight
    COMPUTE(cur);
    cur ^= 1;
  }
  asm volatile("s_waitcnt vmcnt(0)" ::: "memory");
  COMPUTE(cur);
#undef STAGE
#undef COMPUTE

  if (cls != 2) {
    // C[m][n]: lane (lq,lg) holds m = m0+i*16+lg*4+r, n = n0+j*16+lq
    u16* dst = (cls == 0) ? qb : kb;
#pragma unroll
    for (int j = 0; j < 4; j++) {
      const int d  = j*16 + lq;          // head h = nb fixed per block
      const float bv = br[cls * DM + n0 + d];
#pragma unroll
      for (int i = 0; i < 4; i++) {
        const int mb = m0 + i*16 + lg*4;
#pragma unroll
        for (int r = 0; r < 4; r++) {
          const int m = mb + r;
          const int bb = m >> 10, nn = m & 1023;
          dst[(((size_t)(bb * NH + nb)) * NS + nn) * DH + d] = f2bf(acc[i][j][r] + bv);
        }
      }
    }
  } else {
    // C^T[n][m]: lane (lq,lg) holds n = n0+j*16+lg*4+r, m = m0+i*16+lq
#pragma unroll
    for (int j = 0; j < 4; j++) {
      float bvv[4];
#pragma unroll
      for (int r = 0; r < 4; r++)
        bvv[r] = br[2 * DM + n0 + j*16 + lg*4 + r];
#pragma unroll
      for (int i = 0; i < 4; i++) {
        const int m = m0 + i*16 + lq;
        const int bb = m >> 10, nn = m & 1023;
#pragma unroll
        for (int r = 0; r < 4; r++) {
          const int d = j*16 + lg*4 + r;
          vtb[(((size_t)(bb * NH + nb)) * DH + d) * NS + nn] = f2bf(acc[i][j][r] + bvv[r]);
        }
      }
    }
  }
}

// ---------------- flash attention (unchanged from round 3) ----------------
__global__ __launch_bounds__(256) void attn_kernel(
    const u16* __restrict__ qb, const u16* __restrict__ kb,
    const u16* __restrict__ vtb, float* __restrict__ out) {
  __shared__ __align__(16) u16 k_lds[64 * 64];
  __shared__ __align__(16) u16 v_lds[64 * 64];

  const int t = threadIdx.x, w = t >> 6, l = t & 63;
  const int bh = blockIdx.x >> 3, qblk = blockIdx.x & 7;
  const int bb = bh / NH, h = bh % NH;
  const int q0 = qblk * 128 + w * 32;
  const int lq = l & 15, lg = l >> 4;

  bf16x8 qf[2][2];
#pragma unroll
  for (int qt = 0; qt < 2; qt++) {
    const u16* qrow = qb + ((size_t)bh * NS + q0 + qt*16 + lq) * DH;
#pragma unroll
    for (int ds = 0; ds < 2; ds++)
      qf[qt][ds] = *(const bf16x8*)&qrow[lg*8 + ds*32];
  }

  float m2[2]    = {4.0f, 4.0f};
  float lsumP[2] = {0.f, 0.f};
  floatx4 z = {0.f, 0.f, 0.f, 0.f};
  floatx4 o[2][4];
#pragma unroll
  for (int qt = 0; qt < 2; qt++)
#pragma unroll
    for (int dt = 0; dt < 4; dt++) o[qt][dt] = z;

  const int srow = t >> 3;
  const int scb  = (t & 7) ^ (srow & 7);

  for (int kt0 = 0; kt0 < 16; kt0++) {
    const int k0 = kt0 * 64;
    __syncthreads();
#pragma unroll
    for (int i = 0; i < 2; i++) {
      const int row = i*32 + srow;
      gload16(kb  + ((size_t)bh * NS + k0 + row) * DH + scb*8, (char*)k_lds + i*4096 + w*1024);
      gload16(vtb + ((size_t)bh * DH + row) * NS + k0 + scb*8, (char*)v_lds + i*4096 + w*1024);
    }
    __syncthreads();

#pragma unroll
    for (int half = 0; half < 2; half++) {
      bf16x8 kf[2][2];
#pragma unroll
      for (int kt = 0; kt < 2; kt++) {
        const int krow = half*32 + ((lq >> 2) << 3) + kt*4 + (lq & 3);
#pragma unroll
        for (int ds = 0; ds < 2; ds++)
          kf[kt][ds] = *(const bf16x8*)((const char*)k_lds + krow*128 + ((ds*4 + lg) ^ (krow & 7))*16);
      }
      bf16x8 vf[4];
#pragma unroll
      for (int dt = 0; dt < 4; dt++) {
        const int vrow = dt*16 + lq;
        vf[dt] = *(const bf16x8*)((const char*)v_lds + vrow*128 + ((half*4 + lg) ^ (vrow & 7))*16);
      }

#pragma unroll
      for (int qt = 0; qt < 2; qt++) {
        floatx4 st0 = z, st1 = z;
        st0 = __builtin_amdgcn_mfma_f32_16x16x32_bf16(kf[0][0], qf[qt][0], st0, 0, 0, 0);
        st0 = __builtin_amdgcn_mfma_f32_16x16x32_bf16(kf[0][1], qf[qt][1], st0, 0, 0, 0);
        st1 = __builtin_amdgcn_mfma_f32_16x16x32_bf16(kf[1][0], qf[qt][0], st1, 0, 0, 0);
        st1 = __builtin_amdgcn_mfma_f32_16x16x32_bf16(kf[1][1], qf[qt][1], st1, 0, 0, 0);

        float p[8];
#pragma unroll
        for (int r = 0; r < 4; r++) { p[r] = st0[r]; p[4 + r] = st1[r]; }
        const float pmax = fmaxf(fmaxf(fmaxf(p[0], p[1]), fmaxf(p[2], p[3])),
                                 fmaxf(fmaxf(p[4], p[5]), fmaxf(p[6], p[7])));

        if (!__all(pmax - m2[qt] <= 8.0f)) {
          float mt = pmax;
          mt = fmaxf(mt, __shfl_xor(mt, 16));
          mt = fmaxf(mt, __shfl_xor(mt, 32));
          const float mnew = fmaxf(m2[qt], mt);
          const float corr = exp2f(m2[qt] - mnew);
          lsumP[qt] *= corr;
          float cr[4];
#pragma unroll
          for (int r = 0; r < 4; r++) cr[r] = __shfl(corr, lg*4 + r);
#pragma unroll
          for (int dt = 0; dt < 4; dt++)
#pragma unroll
            for (int r = 0; r < 4; r++) o[qt][dt][r] *= cr[r];
          m2[qt] = mnew;
        }

        const float m = m2[qt];
        float ls = 0.f;
        u16 pb[8];
#pragma unroll
        for (int e = 0; e < 8; e++) {
          const float pe = exp2f(p[e] - m);
          ls += pe;
          pb[e] = f2bf(pe);
        }
        lsumP[qt] += ls;

        uint32x4 pw;
        pw.x = (uint32_t)pb[0] | ((uint32_t)pb[1] << 16);
        pw.y = (uint32_t)pb[2] | ((uint32_t)pb[3] << 16);
        pw.z = (uint32_t)pb[4] | ((uint32_t)pb[5] << 16);
        pw.w = (uint32_t)pb[6] | ((uint32_t)pb[7] << 16);
        const bf16x8 pa = __builtin_bit_cast(bf16x8, pw);

#pragma unroll
        for (int dt = 0; dt < 4; dt++)
          o[qt][dt] = __builtin_amdgcn_mfma_f32_16x16x32_bf16(pa, vf[dt], o[qt][dt], 0, 0, 0);
      }
    }
  }

#pragma unroll
  for (int qt = 0; qt < 2; qt++) {
    float ls = lsumP[qt];
    ls += __shfl_xor(ls, 16);
    ls += __shfl_xor(ls, 32);
    const float inv = 1.0f / ls;
    float ir[4];
#pragma unroll
    for (int r = 0; r < 4; r++) ir[r] = __shfl(inv, lg*4 + r);
#pragma unroll
    for (int dt = 0; dt < 4; dt++)
#pragma unroll
      for (int r = 0; r < 4; r++) {
        const int n = q0 + qt*16 + lg*4 + r;
        out[((size_t)bb * NS + n) * DM + h*DH + dt*16 + lq] = o[qt][dt][r] * ir[r];
      }
  }
}

extern "C" void kernel_launch(void* const* d_in, const int* in_sizes, int n_in,
                              void* d_out, int out_size, void* d_ws, size_t ws_size,
                              hipStream_t stream) {
  const float* x     = (const float*)d_in[0];
  const float* w_qkv = (const float*)d_in[1];
  const float* b_qkv = (const float*)d_in[2];
  float* out = (float*)d_out;
  char* ws = (char*)d_ws;

  u16* xb   = (u16*)(ws + WS_XB);
  u16* wt   = (u16*)(ws + WS_WT);
  float* br = (float*)(ws + WS_BR);
  u16* qb   = (u16*)(ws + WS_QB);
  u16* kb   = (u16*)(ws + WS_KB);
  u16* vtb  = (u16*)(ws + WS_VT);

  conv_x_kernel<<<1024, 256, 0, stream>>>((const float4*)x, xb, MTOT * DM / 4);
  prep_bias_kernel<<<9, 256, 0, stream>>>(b_qkv, br);
  transpose_w_kernel<<<dim3(NE/32, DM/32), dim3(32, 8), 0, stream>>>(w_qkv, wt);
  qkv_gemm_kernel<<<4608, 64, 0, stream>>>(xb, wt, br, qb, kb, vtb);
  attn_kernel<<<(NB*NH) * (NS/128), 256, 0, stream>>>(qb, kb, vtb, out);
}

// Round 8
// 132.032 us; speedup vs baseline: 1.2634x; 1.0097x over previous
//
#include <hip/hip_runtime.h>
#include <hip/hip_bf16.h>
#include <stdint.h>

#define NB 8
#define NS 1024
#define DM 768
#define NH 12
#define DH 64
#define NE 2304            // 3*DM
#define MTOT (NB*NS)       // 8192

typedef unsigned short u16;
typedef __attribute__((ext_vector_type(8))) __bf16 bf16x8;
typedef __attribute__((ext_vector_type(4))) float floatx4;
typedef __attribute__((ext_vector_type(4))) uint32_t uint32x4;

// ---- workspace layout (bytes) ----
#define WS_XB  0ull                    // x bf16 [8192][768]
#define WS_WT  12582912ull             // wt bf16 [3][768 n=h*64+d][768 k]
#define WS_BR  16121856ull             // bias f32 [3][768] (Q prescaled)
#define WS_QB  16131072ull             // Q bf16 [96][1024][64] (pre-scaled)
#define WS_KB  28713984ull             // K bf16 [96][1024][64]
#define WS_VT  41296896ull             // V^T bf16 [96][64][1024]

#define QSC 0.05206490030275093f       // 768^-0.5 * log2(e)

__device__ __forceinline__ u16 f2bf(float f) {
  union { float f; uint32_t u; } v; v.f = f;
  uint32_t r = (v.u + 0x7fffu + ((v.u >> 16) & 1u)) >> 16;   // RNE
  return (u16)r;
}

__device__ __forceinline__ void gload16(const void* g, void* l) {
  __builtin_amdgcn_global_load_lds(
      (const __attribute__((address_space(1))) void*)g,
      (__attribute__((address_space(3))) void*)l, 16, 0, 0);
}

// ---------------- convert x -> bf16 ----------------
__global__ void conv_x_kernel(const float4* __restrict__ x, u16* __restrict__ xb, int n4) {
  int i = blockIdx.x * blockDim.x + threadIdx.x;
  int stride = gridDim.x * blockDim.x;
  for (; i < n4; i += stride) {
    float4 v = x[i];
    ushort4 r;
    r.x = f2bf(v.x); r.y = f2bf(v.y); r.z = f2bf(v.z); r.w = f2bf(v.w);
    ((ushort4*)xb)[i] = r;
  }
}

// ---------------- bias de-interleave: br[c][h*64+d] = b[h*192+d*3+c] ----------------
__global__ void prep_bias_kernel(const float* __restrict__ b, float* __restrict__ br) {
  const int o = blockIdx.x * 256 + threadIdx.x;
  if (o < 3 * DM) {
    const int c = o / DM, n = o % DM;
    const int h = n >> 6, d = n & 63;
    float v = b[h * 192 + d * 3 + c];
    if (c == 0) v *= QSC;
    br[o] = v;
  }
}

// ---------------- weights: w[768k][2304e] f32 -> wt[c][n=h*64+d][k] bf16 ----------------
__global__ void transpose_w_kernel(const float* __restrict__ w, u16* __restrict__ wt) {
  __shared__ float tile[32][33];
  const int e0 = blockIdx.x * 32, k0 = blockIdx.y * 32;
  const int tx = threadIdx.x, ty = threadIdx.y;   // block (32,8)
#pragma unroll
  for (int i = 0; i < 4; i++)
    tile[ty + i*8][tx] = w[(size_t)(k0 + ty + i*8) * NE + e0 + tx];
  __syncthreads();
#pragma unroll
  for (int i = 0; i < 4; i++) {
    const int e = e0 + ty + i*8;
    const int c = e % 3, h = e / 192, d = (e % 192) / 3;
    const float sc = (c == 0) ? QSC : 1.0f;
    wt[((size_t)c * DM + h*64 + d) * DM + k0 + tx] = f2bf(tile[tx][ty + i*8] * sc);
  }
}

// ---------------- unified QKV GEMM: 1-wave blocks, barrier-free depth-2 pipeline ----
// 64x64 tile per 64-thread block; 4608 blocks; triple-buffered LDS (24KB).
// In-flight: 3 tiles (24 loads); vmcnt(16) retires only the tile about to be
// computed. All buffer indices static (unroll-by-3). No __syncthreads anywhere.
// Q/K: acc=mfma(af,bfr)->C[m][n];  V: acc=mfma(bfr,af)->C^T[n][m].
__global__ __launch_bounds__(64, 4) void qkv_gemm_kernel(
    const u16* __restrict__ xb, const u16* __restrict__ wt,
    const float* __restrict__ br,
    u16* __restrict__ qb, u16* __restrict__ kb, u16* __restrict__ vtb) {
  __shared__ __align__(16) u16 a_lds[3][64 * 32];
  __shared__ __align__(16) u16 b_lds[3][64 * 32];
  const int t  = threadIdx.x;            // 0..63
  const int lq = t & 15, lg = t >> 4;

  const int bid    = (int)blockIdx.x;
  const int xcd    = bid & 7;
  const int within = bid >> 3;           // 0..575
  const int mi     = within & 15;        // m fastest: share wt panel in L2
  const int ni     = within >> 4;        // 0..35
  const int m0     = (xcd * 16 + mi) * 64;
  const int cls    = ni / 12;
  const int nb     = ni % 12;
  const int n0     = nb * 64;

  floatx4 z = {0.f, 0.f, 0.f, 0.f};
  floatx4 acc[4][4];
#pragma unroll
  for (int i = 0; i < 4; i++)
#pragma unroll
    for (int j = 0; j < 4; j++) acc[i][j] = z;

  // staging: gload i covers rows i*16 + t/4; 16B-block (t&3) ^ ((row>>1)&3)
  const int srow = t >> 2;               // 0..15
  const int scb  = (t & 3) ^ ((t >> 3) & 3);
  const u16* ga = xb + (size_t)m0 * DM + scb * 8;
  const u16* gb = wt + ((size_t)cls * DM + n0) * DM + scb * 8;
  const int rswz = (lq >> 1) & 3;

#define STAGE(buf, k0)                                                            \
  {                                                                               \
    _Pragma("unroll")                                                             \
    for (int i = 0; i < 4; i++) {                                                 \
      gload16(ga + (size_t)(i*16 + srow) * DM + (k0), (char*)a_lds[buf] + i*1024); \
      gload16(gb + (size_t)(i*16 + srow) * DM + (k0), (char*)b_lds[buf] + i*1024); \
    }                                                                             \
  }

#define COMPUTE(buf)                                                              \
  {                                                                               \
    bf16x8 af[4], bfr[4];                                                         \
    _Pragma("unroll")                                                             \
    for (int i = 0; i < 4; i++)                                                   \
      af[i] = *(const bf16x8*)((const char*)a_lds[buf] + (i*16 + lq)*64 + ((lg ^ rswz) * 16)); \
    _Pragma("unroll")                                                             \
    for (int j = 0; j < 4; j++)                                                   \
      bfr[j] = *(const bf16x8*)((const char*)b_lds[buf] + (j*16 + lq)*64 + ((lg ^ rswz) * 16)); \
    if (cls == 2) {                                                               \
      _Pragma("unroll")                                                           \
      for (int i = 0; i < 4; i++)                                                 \
        _Pragma("unroll")                                                         \
        for (int j = 0; j < 4; j++)                                               \
          acc[i][j] = __builtin_amdgcn_mfma_f32_16x16x32_bf16(bfr[j], af[i], acc[i][j], 0, 0, 0); \
    } else {                                                                      \
      _Pragma("unroll")                                                           \
      for (int i = 0; i < 4; i++)                                                 \
        _Pragma("unroll")                                                         \
        for (int j = 0; j < 4; j++)                                               \
          acc[i][j] = __builtin_amdgcn_mfma_f32_16x16x32_bf16(af[i], bfr[j], acc[i][j], 0, 0, 0); \
    }                                                                             \
  }

#define LGK0  asm volatile("s_waitcnt lgkmcnt(0)" ::: "memory")
#define VM(n) asm volatile("s_waitcnt vmcnt(" #n ")" ::: "memory")

  // prologue: tiles 0,1 in flight (16 loads)
  STAGE(0, 0);
  STAGE(1, 32);
  // main: 7 unrolled triples covering tiles 0..20 (stage through tile 22)
  for (int kb = 0; kb < 7; ++kb) {
    const int kk = kb * 96;
    LGK0; STAGE(2, kk + 64);  VM(16); COMPUTE(0);   // compute tile 3kb
    LGK0; STAGE(0, kk + 96);  VM(16); COMPUTE(1);   // compute tile 3kb+1
    LGK0; STAGE(1, kk + 128); VM(16); COMPUTE(2);   // compute tile 3kb+2
  }
  // tail: tiles 21,22,23
  LGK0; STAGE(2, 736); VM(16); COMPUTE(0);          // tile 21 (stage tile 23)
  VM(8);  COMPUTE(1);                               // tile 22
  VM(0);  COMPUTE(2);                               // tile 23
#undef STAGE
#undef COMPUTE
#undef LGK0
#undef VM

  if (cls != 2) {
    // C[m][n]: lane (lq,lg) holds m = m0+i*16+lg*4+r, n = n0+j*16+lq
    u16* dst = (cls == 0) ? qb : kb;
#pragma unroll
    for (int j = 0; j < 4; j++) {
      const int d  = j*16 + lq;          // head h = nb fixed per block
      const float bv = br[cls * DM + n0 + d];
#pragma unroll
      for (int i = 0; i < 4; i++) {
        const int mb = m0 + i*16 + lg*4;
#pragma unroll
        for (int r = 0; r < 4; r++) {
          const int m = mb + r;
          const int bb = m >> 10, nn = m & 1023;
          dst[(((size_t)(bb * NH + nb)) * NS + nn) * DH + d] = f2bf(acc[i][j][r] + bv);
        }
      }
    }
  } else {
    // C^T[n][m]: lane (lq,lg) holds n = n0+j*16+lg*4+r, m = m0+i*16+lq
#pragma unroll
    for (int j = 0; j < 4; j++) {
      float bvv[4];
#pragma unroll
      for (int r = 0; r < 4; r++)
        bvv[r] = br[2 * DM + n0 + j*16 + lg*4 + r];
#pragma unroll
      for (int i = 0; i < 4; i++) {
        const int m = m0 + i*16 + lq;
        const int bb = m >> 10, nn = m & 1023;
#pragma unroll
        for (int r = 0; r < 4; r++) {
          const int d = j*16 + lg*4 + r;
          vtb[(((size_t)(bb * NH + nb)) * DH + d) * NS + nn] = f2bf(acc[i][j][r] + bvv[r]);
        }
      }
    }
  }
}

// ---------------- flash attention (unchanged from round 3) ----------------
__global__ __launch_bounds__(256) void attn_kernel(
    const u16* __restrict__ qb, const u16* __restrict__ kb,
    const u16* __restrict__ vtb, float* __restrict__ out) {
  __shared__ __align__(16) u16 k_lds[64 * 64];
  __shared__ __align__(16) u16 v_lds[64 * 64];

  const int t = threadIdx.x, w = t >> 6, l = t & 63;
  const int bh = blockIdx.x >> 3, qblk = blockIdx.x & 7;
  const int bb = bh / NH, h = bh % NH;
  const int q0 = qblk * 128 + w * 32;
  const int lq = l & 15, lg = l >> 4;

  bf16x8 qf[2][2];
#pragma unroll
  for (int qt = 0; qt < 2; qt++) {
    const u16* qrow = qb + ((size_t)bh * NS + q0 + qt*16 + lq) * DH;
#pragma unroll
    for (int ds = 0; ds < 2; ds++)
      qf[qt][ds] = *(const bf16x8*)&qrow[lg*8 + ds*32];
  }

  float m2[2]    = {4.0f, 4.0f};
  float lsumP[2] = {0.f, 0.f};
  floatx4 z = {0.f, 0.f, 0.f, 0.f};
  floatx4 o[2][4];
#pragma unroll
  for (int qt = 0; qt < 2; qt++)
#pragma unroll
    for (int dt = 0; dt < 4; dt++) o[qt][dt] = z;

  const int srow = t >> 3;
  const int scb  = (t & 7) ^ (srow & 7);

  for (int kt0 = 0; kt0 < 16; kt0++) {
    const int k0 = kt0 * 64;
    __syncthreads();
#pragma unroll
    for (int i = 0; i < 2; i++) {
      const int row = i*32 + srow;
      gload16(kb  + ((size_t)bh * NS + k0 + row) * DH + scb*8, (char*)k_lds + i*4096 + w*1024);
      gload16(vtb + ((size_t)bh * DH + row) * NS + k0 + scb*8, (char*)v_lds + i*4096 + w*1024);
    }
    __syncthreads();

#pragma unroll
    for (int half = 0; half < 2; half++) {
      bf16x8 kf[2][2];
#pragma unroll
      for (int kt = 0; kt < 2; kt++) {
        const int krow = half*32 + ((lq >> 2) << 3) + kt*4 + (lq & 3);
#pragma unroll
        for (int ds = 0; ds < 2; ds++)
          kf[kt][ds] = *(const bf16x8*)((const char*)k_lds + krow*128 + ((ds*4 + lg) ^ (krow & 7))*16);
      }
      bf16x8 vf[4];
#pragma unroll
      for (int dt = 0; dt < 4; dt++) {
        const int vrow = dt*16 + lq;
        vf[dt] = *(const bf16x8*)((const char*)v_lds + vrow*128 + ((half*4 + lg) ^ (vrow & 7))*16);
      }

#pragma unroll
      for (int qt = 0; qt < 2; qt++) {
        floatx4 st0 = z, st1 = z;
        st0 = __builtin_amdgcn_mfma_f32_16x16x32_bf16(kf[0][0], qf[qt][0], st0, 0, 0, 0);
        st0 = __builtin_amdgcn_mfma_f32_16x16x32_bf16(kf[0][1], qf[qt][1], st0, 0, 0, 0);
        st1 = __builtin_amdgcn_mfma_f32_16x16x32_bf16(kf[1][0], qf[qt][0], st1, 0, 0, 0);
        st1 = __builtin_amdgcn_mfma_f32_16x16x32_bf16(kf[1][1], qf[qt][1], st1, 0, 0, 0);

        float p[8];
#pragma unroll
        for (int r = 0; r < 4; r++) { p[r] = st0[r]; p[4 + r] = st1[r]; }
        const float pmax = fmaxf(fmaxf(fmaxf(p[0], p[1]), fmaxf(p[2], p[3])),
                                 fmaxf(fmaxf(p[4], p[5]), fmaxf(p[6], p[7])));

        if (!__all(pmax - m2[qt] <= 8.0f)) {
          float mt = pmax;
          mt = fmaxf(mt, __shfl_xor(mt, 16));
          mt = fmaxf(mt, __shfl_xor(mt, 32));
          const float mnew = fmaxf(m2[qt], mt);
          const float corr = exp2f(m2[qt] - mnew);
          lsumP[qt] *= corr;
          float cr[4];
#pragma unroll
          for (int r = 0; r < 4; r++) cr[r] = __shfl(corr, lg*4 + r);
#pragma unroll
          for (int dt = 0; dt < 4; dt++)
#pragma unroll
            for (int r = 0; r < 4; r++) o[qt][dt][r] *= cr[r];
          m2[qt] = mnew;
        }

        const float m = m2[qt];
        float ls = 0.f;
        u16 pb[8];
#pragma unroll
        for (int e = 0; e < 8; e++) {
          const float pe = exp2f(p[e] - m);
          ls += pe;
          pb[e] = f2bf(pe);
        }
        lsumP[qt] += ls;

        uint32x4 pw;
        pw.x = (uint32_t)pb[0] | ((uint32_t)pb[1] << 16);
        pw.y = (uint32_t)pb[2] | ((uint32_t)pb[3] << 16);
        pw.z = (uint32_t)pb[4] | ((uint32_t)pb[5] << 16);
        pw.w = (uint32_t)pb[6] | ((uint32_t)pb[7] << 16);
        const bf16x8 pa = __builtin_bit_cast(bf16x8, pw);

#pragma unroll
        for (int dt = 0; dt < 4; dt++)
          o[qt][dt] = __builtin_amdgcn_mfma_f32_16x16x32_bf16(pa, vf[dt], o[qt][dt], 0, 0, 0);
      }
    }
  }

#pragma unroll
  for (int qt = 0; qt < 2; qt++) {
    float ls = lsumP[qt];
    ls += __shfl_xor(ls, 16);
    ls += __shfl_xor(ls, 32);
    const float inv = 1.0f / ls;
    float ir[4];
#pragma unroll
    for (int r = 0; r < 4; r++) ir[r] = __shfl(inv, lg*4 + r);
#pragma unroll
    for (int dt = 0; dt < 4; dt++)
#pragma unroll
      for (int r = 0; r < 4; r++) {
        const int n = q0 + qt*16 + lg*4 + r;
        out[((size_t)bb * NS + n) * DM + h*DH + dt*16 + lq] = o[qt][dt][r] * ir[r];
      }
  }
}

extern "C" void kernel_launch(void* const* d_in, const int* in_sizes, int n_in,
                              void* d_out, int out_size, void* d_ws, size_t ws_size,
                              hipStream_t stream) {
  const float* x     = (const float*)d_in[0];
  const float* w_qkv = (const float*)d_in[1];
  const float* b_qkv = (const float*)d_in[2];
  float* out = (float*)d_out;
  char* ws = (char*)d_ws;

  u16* xb   = (u16*)(ws + WS_XB);
  u16* wt   = (u16*)(ws + WS_WT);
  float* br = (float*)(ws + WS_BR);
  u16* qb   = (u16*)(ws + WS_QB);
  u16* kb   = (u16*)(ws + WS_KB);
  u16* vtb  = (u16*)(ws + WS_VT);

  conv_x_kernel<<<1024, 256, 0, stream>>>((const float4*)x, xb, MTOT * DM / 4);
  prep_bias_kernel<<<9, 256, 0, stream>>>(b_qkv, br);
  transpose_w_kernel<<<dim3(NE/32, DM/32), dim3(32, 8), 0, stream>>>(w_qkv, wt);
  qkv_gemm_kernel<<<4608, 64, 0, stream>>>(xb, wt, br, qb, kb, vtb);
  attn_kernel<<<(NB*NH) * (NS/128), 256, 0, stream>>>(qb, kb, vtb, out);
}